// Round 7
// baseline (1015.761 us; speedup 1.0000x reference)
//
#include <hip/hip_runtime.h>
#include <hip/hip_fp16.h>

#define D 128
#define CAP1 80  // d1, d2 buckets (mean degree 32)
#define CAP2 56  // d12, s1, s2 buckets (mean degree 16)

typedef short s16x8 __attribute__((ext_vector_type(8)));
typedef float f32x4 __attribute__((ext_vector_type(4)));

// ===========================================================================
// ELL fill job descriptor (passed by value, one kernel per job)
// Weighted payloads packed into one int: (idx << 15) | round(w * 32768).
// ===========================================================================
struct FillJob {
    const int* key;    // bucket node id per edge
    const int* other;  // payload index per edge
    const float* w;    // weight (nullptr -> raw index payload)
    int* pay;          // payload at key*cap + slot
    int cbase;         // node base in concatenated cursor space
    int cap;           // bucket capacity
    int E, N;
};

// ===========================================================================
// XCD-partitioned ELL fill, one job per dispatch (stream-serialized).
// Blocks round-robin over 8 XCDs (blockIdx.x & 7); each XCD-group owns key
// range [N*x/8, N*(x+1)/8) so payload lines are written by one L2.
// ===========================================================================
__global__ __launch_bounds__(256) void fill_job_kernel(FillJob jb,
                                                       int* __restrict__ cursor) {
    int x = blockIdx.x & 7;   // ~XCD id
    int gb = blockIdx.x >> 3; // block index within XCD-group
    int lo = (int)((long)jb.N * x / 8);
    int hi = (int)((long)jb.N * (x + 1) / 8);
    bool hasw = (jb.w != nullptr);
    long stride = (long)(gridDim.x >> 3) * 256;
    for (long e = (long)gb * 256 + threadIdx.x; e < jb.E; e += stride) {
        int key = jb.key[e];
        if (key < lo || key >= hi) continue;
        int pos = atomicAdd(&cursor[jb.cbase + key], 1);
        if (pos >= jb.cap) continue;  // overflow guard (prob ~1e-7 total)
        int o = jb.other[e];
        int v;
        if (hasw) {
            int w15 = __float2int_rn(jb.w[e] * 32768.0f);
            w15 = w15 > 32767 ? 32767 : w15;
            v = (int)(((unsigned)o << 15) | (unsigned)w15);
        } else {
            v = o;
        }
        jb.pay[(long)key * jb.cap + pos] = v;
    }
}

// ===========================================================================
// fp32 -> fp16 conversion (x_node table)
// ===========================================================================
__global__ void f2h_kernel(const float2* __restrict__ in, __half2* __restrict__ o,
                           long n2) {
    long i = (long)blockIdx.x * blockDim.x + threadIdx.x;
    if (i < n2) o[i] = __float22half2_rn(in[i]);
}

// ===========================================================================
// Split W (3 x 128 x 128 fp32) into bf16 hi/lo pair: W = hi + lo + O(2^-16).
// ===========================================================================
__global__ void wsplit_kernel(const float* __restrict__ W1,
                              const float* __restrict__ W2,
                              const float* __restrict__ W12,
                              unsigned short* __restrict__ hi,
                              unsigned short* __restrict__ lo) {
    int i = blockIdx.x * 256 + threadIdx.x;
    if (i >= 3 * D * D) return;
    int p = i >> 14, r = i & (D * D - 1);
    const float* W = p == 0 ? W1 : (p == 1 ? W2 : W12);
    float x = W[r];
    unsigned u = __float_as_uint(x);
    unsigned hb = u & 0xFFFF0000u;
    hi[i] = (unsigned short)(hb >> 16);
    float rem = x - __uint_as_float(hb);
    lo[i] = (unsigned short)(__float_as_uint(rem) >> 16);
}

// ===========================================================================
// Wide-gather aggregation: 16B/lane float4 loads. R1/R2 established these
// kernels are L2-miss-path bound (dur == FETCH/3.1TB/s); lowest-VGPR form.
// ===========================================================================
__device__ __forceinline__ void acc8(float4 raw, float mul, float2 a[4]) {
    const __half2* h = (const __half2*)&raw;
#pragma unroll
    for (int k = 0; k < 4; ++k) {
        float2 f = __half22float2(h[k]);
        a[k].x = fmaf(f.x, mul, a[k].x);
        a[k].y = fmaf(f.y, mul, a[k].y);
    }
}

// Stage-1: gather fp16 rows, fp32 accumulate, combine with fp32 xb,
// write fp16 row at dst[node*dstride + doff]. One wave per node.
template <bool HASW>
__global__ __launch_bounds__(256) void aggh_kernel(
    const __half* __restrict__ vals, int vstride, const int* __restrict__ cnt,
    int cap, const int* __restrict__ pay, const float* __restrict__ xb,
    __half* __restrict__ dst, int dstride, int doff, int N) {
    int node = (int)(((long)blockIdx.x * 256 + threadIdx.x) >> 6);
    int lane = threadIdx.x & 63;
    if (node >= N) return;
    int count = cnt[node];
    int m = count < cap ? count : cap;
    long b0 = (long)node * cap;
    int grp = lane >> 4, il = lane & 15;
    float2 a[4] = {{0.f, 0.f}, {0.f, 0.f}, {0.f, 0.f}, {0.f, 0.f}};
    for (int base = 0; base < m; base += 64) {
        int rem = m - base;
        int n = rem < 64 ? rem : 64;
        int p = 0;
        if (lane < n) p = pay[b0 + base + lane];
        for (int j = 0; j < n; j += 4) {
            int jj = j + grp;
            int pj = __shfl(p, jj, 64);
            int g;
            float wt;
            if (HASW) {
                g = (int)(((unsigned)pj) >> 15);
                wt = (float)(pj & 0x7fff) * (1.0f / 32768.0f);
            } else {
                g = pj;
                wt = 1.0f;
            }
            float mul = jj < n ? wt : 0.0f;
            float4 raw = ((const float4*)(vals + (long)g * vstride))[il];
            acc8(raw, mul, a);
        }
    }
#pragma unroll
    for (int k = 0; k < 4; ++k) {
        a[k].x += __shfl_xor(a[k].x, 16, 64);
        a[k].y += __shfl_xor(a[k].y, 16, 64);
        a[k].x += __shfl_xor(a[k].x, 32, 64);
        a[k].y += __shfl_xor(a[k].y, 32, 64);
    }
    if (lane < 16) {
        float inv = 1.0f / fmaxf((float)count, 1.0f);
        const float4* xp = (const float4*)(xb + (long)node * D + il * 8);
        float4 x0 = xp[0], x1 = xp[1];
        float rx[8] = {x0.x, x0.y, x0.z, x0.w, x1.x, x1.y, x1.z, x1.w};
        __half2 h[4];
#pragma unroll
        for (int k = 0; k < 4; ++k) {
            float2 r;
            r.x = (a[k].x * inv + rx[2 * k + 0]) * 0.5f;
            r.y = (a[k].y * inv + rx[2 * k + 1]) * 0.5f;
            h[k] = __float22half2_rn(r);
        }
        *(float4*)(dst + (long)node * dstride + doff + il * 8) = *(float4*)h;
    }
}

// Stage-2: pre1 = mean over fp16 net1h rows, fp32 output, no combine.
__global__ __launch_bounds__(256) void aggf_kernel(
    const __half* __restrict__ vals, const int* __restrict__ cnt, int cap,
    const int* __restrict__ pay, float* __restrict__ out, int N) {
    int node = (int)(((long)blockIdx.x * 256 + threadIdx.x) >> 6);
    int lane = threadIdx.x & 63;
    if (node >= N) return;
    int count = cnt[node];
    int m = count < cap ? count : cap;
    long b0 = (long)node * cap;
    int grp = lane >> 4, il = lane & 15;
    float2 a[4] = {{0.f, 0.f}, {0.f, 0.f}, {0.f, 0.f}, {0.f, 0.f}};
    for (int base = 0; base < m; base += 64) {
        int rem = m - base;
        int n = rem < 64 ? rem : 64;
        int p = 0;
        if (lane < n) p = pay[b0 + base + lane];
        for (int j = 0; j < n; j += 4) {
            int jj = j + grp;
            int pj = __shfl(p, jj, 64);
            float mul = jj < n ? 1.0f : 0.0f;
            float4 raw = ((const float4*)(vals + (long)pj * D))[il];
            acc8(raw, mul, a);
        }
    }
#pragma unroll
    for (int k = 0; k < 4; ++k) {
        a[k].x += __shfl_xor(a[k].x, 16, 64);
        a[k].y += __shfl_xor(a[k].y, 16, 64);
        a[k].x += __shfl_xor(a[k].x, 32, 64);
        a[k].y += __shfl_xor(a[k].y, 32, 64);
    }
    if (lane < 16) {
        float inv = 1.0f / fmaxf((float)count, 1.0f);
        float4* op = (float4*)(out + (long)node * D + il * 8);
        float4 o0 = {a[0].x * inv, a[0].y * inv, a[1].x * inv, a[1].y * inv};
        float4 o1 = {a[2].x * inv, a[2].y * inv, a[3].x * inv, a[3].y * inv};
        op[0] = o0;
        op[1] = o1;
    }
}

// Fused pre2/pre3: combo rows hold [net2h | net2bh] (256 halves, 512B).
// Requires cap <= 64 (cap = CAP2 = 56): single payload batch.
__global__ __launch_bounds__(256) void agg2_kernel(
    const __half* __restrict__ combo, const int* __restrict__ cnt, int cap,
    const int* __restrict__ pay, float* __restrict__ outa,
    float* __restrict__ outb, int N) {
    int node = (int)(((long)blockIdx.x * 256 + threadIdx.x) >> 6);
    int lane = threadIdx.x & 63;
    if (node >= N) return;
    int count = cnt[node];
    int m = count < cap ? count : cap;
    long b0 = (long)node * cap;
    int grp = lane >> 5, il = lane & 31;
    float2 a[4] = {{0.f, 0.f}, {0.f, 0.f}, {0.f, 0.f}, {0.f, 0.f}};
    int p = 0;
    if (lane < m) p = pay[b0 + lane];
    for (int j = 0; j < m; j += 2) {
        int jj = j + grp;
        int pj = __shfl(p, jj, 64);
        int g = (int)(((unsigned)pj) >> 15);
        float w = (float)(pj & 0x7fff) * (1.0f / 32768.0f);
        float mul = jj < m ? (il < 16 ? 1.0f : w) : 0.0f;
        float4 raw = ((const float4*)(combo + (long)g * 256))[il];
        acc8(raw, mul, a);
    }
#pragma unroll
    for (int k = 0; k < 4; ++k) {
        a[k].x += __shfl_xor(a[k].x, 32, 64);
        a[k].y += __shfl_xor(a[k].y, 32, 64);
    }
    if (lane < 32) {
        float inv = 1.0f / fmaxf((float)count, 1.0f);
        float* o = (il < 16) ? (outa + (long)node * D + il * 8)
                             : (outb + (long)node * D + (il - 16) * 8);
        float4 o0 = {a[0].x * inv, a[0].y * inv, a[1].x * inv, a[1].y * inv};
        float4 o1 = {a[2].x * inv, a[2].y * inv, a[3].x * inv, a[3].y * inv};
        ((float4*)o)[0] = o0;
        ((float4*)o)[1] = o1;
    }
}

// ===========================================================================
// MFMA tail v2: out = attn(relu(pre_p @ Wp^T + bp)) via split-bf16 MFMA.
// R6 PMC: v1 (16x128 per wave) was latency-bound: VGPR 144 -> ~2 waves/SIMD,
// and 192 just-in-time 16B W loads per wave from L2 -> 85% stall, 196 us.
// v2: 16 rows x 64 cols per wave (acc 96->48 VGPR, __launch_bounds__(256,4)
// caps VGPR at 128 -> 4 waves/SIMD). Block = 4 waves = 2 row-strips x 2
// col-halves; attention scores combined across the two col-half waves via a
// 768B LDS array + one __syncthreads().
// pre3 aliases out: all loads precede the barrier, stores follow it; blocks
// are row-disjoint -> safe.
// ===========================================================================
__global__ __launch_bounds__(256, 4) void mfma_tail_kernel(
    const float* __restrict__ pre1, const float* __restrict__ pre2,
    const float* pre3, const unsigned short* __restrict__ Whi,
    const unsigned short* __restrict__ Wlo, const float* __restrict__ b1,
    const float* __restrict__ b2, const float* __restrict__ b12,
    const float* __restrict__ att, float* out, int N) {
    __shared__ float sred[2][2][3][16];  // [strip][half][path][row]
    int tid = threadIdx.x;
    int w = tid >> 6, lane = tid & 63;
    int strip = w >> 1, half = w & 1;
    int rw = lane & 15, kg = lane >> 4;
    int m0 = blockIdx.x * 32 + strip * 16;
    int mrow = m0 + rw;
    if (mrow >= N) mrow = N - 1;  // clamp (no early return: barrier below)
    const float* PRE[3] = {pre1, pre2, pre3};
    const float* BB[3] = {b1, b2, b12};

    f32x4 acc[3][4];
#pragma unroll
    for (int p = 0; p < 3; ++p)
#pragma unroll
        for (int c = 0; c < 4; ++c) acc[p][c] = (f32x4){0.f, 0.f, 0.f, 0.f};

#pragma unroll
    for (int p = 0; p < 3; ++p) {
        const float* src = PRE[p] + (long)mrow * D + kg * 8;
        // B fragment: output col = half*64 + c*16 + rw -> W row (same index)
        const unsigned short* whp =
            Whi + ((long)p << 14) + (long)(half * 64 + rw) * D + kg * 8;
        const unsigned short* wlp =
            Wlo + ((long)p << 14) + (long)(half * 64 + rw) * D + kg * 8;
#pragma unroll
        for (int kt = 0; kt < 4; ++kt) {
            float4 xa = *(const float4*)(src + kt * 32);
            float4 xb = *(const float4*)(src + kt * 32 + 4);
            float xs[8] = {xa.x, xa.y, xa.z, xa.w, xb.x, xb.y, xb.z, xb.w};
            s16x8 ah, al;
#pragma unroll
            for (int i = 0; i < 8; ++i) {
                unsigned u = __float_as_uint(xs[i]);
                unsigned hb = u & 0xFFFF0000u;
                ah[i] = (short)(hb >> 16);
                float rem = xs[i] - __uint_as_float(hb);
                al[i] = (short)(__float_as_uint(rem) >> 16);
            }
#pragma unroll
            for (int c = 0; c < 4; ++c) {
                s16x8 bh = *(const s16x8*)(whp + c * (16 * D) + kt * 32);
                s16x8 bl = *(const s16x8*)(wlp + c * (16 * D) + kt * 32);
                acc[p][c] = __builtin_amdgcn_mfma_f32_16x16x32_bf16(
                    ah, bh, acc[p][c], 0, 0, 0);
                acc[p][c] = __builtin_amdgcn_mfma_f32_16x16x32_bf16(
                    ah, bl, acc[p][c], 0, 0, 0);
                acc[p][c] = __builtin_amdgcn_mfma_f32_16x16x32_bf16(
                    al, bh, acc[p][c], 0, 0, 0);
            }
        }
    }

    // bias + relu (in place) + half-row attention partial dots
    float sc[3][4] = {{0.f, 0.f, 0.f, 0.f},
                      {0.f, 0.f, 0.f, 0.f},
                      {0.f, 0.f, 0.f, 0.f}};
#pragma unroll
    for (int p = 0; p < 3; ++p) {
#pragma unroll
        for (int c = 0; c < 4; ++c) {
            int col = half * 64 + c * 16 + rw;
            float bv = BB[p][col];
            float av = att[p * D + col];
#pragma unroll
            for (int j = 0; j < 4; ++j) {
                float v = fmaxf(acc[p][c][j] + bv, 0.0f);
                acc[p][c][j] = v;
                sc[p][j] = fmaf(v, av, sc[p][j]);
            }
        }
    }
    // reduce within 16-lane groups (rows kg*4+j), publish half-row sums
#pragma unroll
    for (int j = 0; j < 4; ++j) {
#pragma unroll
        for (int off = 1; off < 16; off <<= 1) {
            sc[0][j] += __shfl_xor(sc[0][j], off, 64);
            sc[1][j] += __shfl_xor(sc[1][j], off, 64);
            sc[2][j] += __shfl_xor(sc[2][j], off, 64);
        }
    }
    if (rw == 0) {
#pragma unroll
        for (int p = 0; p < 3; ++p)
#pragma unroll
            for (int j = 0; j < 4; ++j)
                sred[strip][half][p][kg * 4 + j] = sc[p][j];
    }
    __syncthreads();

    // combine halves, softmax, blend, store (own 64-col half)
#pragma unroll
    for (int j = 0; j < 4; ++j) {
        int row = kg * 4 + j;
        float s0 = sred[strip][0][0][row] + sred[strip][1][0][row];
        float s1 = sred[strip][0][1][row] + sred[strip][1][1][row];
        float s2 = sred[strip][0][2][row] + sred[strip][1][2][row];
        float mx = fmaxf(s0, fmaxf(s1, s2));
        float e0 = __expf(s0 - mx), e1 = __expf(s1 - mx), e2 = __expf(s2 - mx);
        float inv = 1.0f / (e0 + e1 + e2);
        float w0 = e0 * inv, w1 = e1 * inv, w2 = e2 * inv;
        int orow = m0 + row;
        if (orow < N) {
            long ro = (long)orow * D + half * 64 + rw;
#pragma unroll
            for (int c = 0; c < 4; ++c) {
                out[ro + c * 16] =
                    acc[0][c][j] * w0 + acc[1][c][j] * w1 + acc[2][c][j] * w2;
            }
        }
    }
}

// ===========================================================================
extern "C" void kernel_launch(void* const* d_in, const int* in_sizes, int n_in,
                              void* d_out, int out_size, void* d_ws,
                              size_t ws_size, hipStream_t stream) {
    const float* x_node = (const float*)d_in[0];
    const float* x1 = (const float*)d_in[1];
    const float* x2 = (const float*)d_in[2];
    const int* ei1_src = (const int*)d_in[3];
    const int* ei1_dst = (const int*)d_in[4];
    const int* ei2_src = (const int*)d_in[5];
    const int* ei2_dst = (const int*)d_in[6];
    const int* ei12_src = (const int*)d_in[7];
    const int* ei12_dst = (const int*)d_in[8];
    const float* ew1 = (const float*)d_in[9];
    const float* ew2 = (const float*)d_in[10];
    const float* W1 = (const float*)d_in[11];
    const float* b1 = (const float*)d_in[12];
    const float* W2 = (const float*)d_in[13];
    const float* b2 = (const float*)d_in[14];
    const float* W12 = (const float*)d_in[15];
    const float* b12 = (const float*)d_in[16];
    const float* att = (const float*)d_in[17];
    float* out = (float*)d_out;

    const int N0 = in_sizes[0] / D;
    const int N1 = in_sizes[1] / D;
    const int N2 = in_sizes[2] / D;
    const int E1 = in_sizes[3];
    const int E2 = in_sizes[5];
    const int E12 = in_sizes[7];

    float* ws = (float*)d_ws;
    size_t off = 0;
    auto A = [](size_t v) { return (v + 3) & ~(size_t)3; };  // 16B align (words)

    // fp16 tables
    __half* xh = (__half*)(ws + off);    off += A((size_t)N0 * D / 2);
    __half* net1h = (__half*)(ws + off); off += A((size_t)N1 * D / 2);
    __half* combo = (__half*)(ws + off); off += A((size_t)N2 * D);  // 256 h/row

    // --- ELL payload block A: pay_d12, pay_s1 (dead after aggf) ---
    // pre2 aliases this block (written by agg2, after both are dead).
    size_t pA = off;
    int* pay_d12 = (int*)(ws + off); off += A((size_t)N2 * CAP2);
    int* pay_s1 = (int*)(ws + off);  off += A((size_t)N0 * CAP2);
    size_t needA = pA + (size_t)N0 * D;  // pre2 words
    if (off < needA) off = needA;
    float* pre2 = ws + pA;

    // --- ELL payload block B: pay_d1, pay_d2 (dead after aggh d1/d2) ---
    // pre1 aliases this block (written by aggf, after both are dead).
    size_t pB = off;
    int* pay_d1 = (int*)(ws + off); off += A((size_t)N1 * CAP1);
    int* pay_d2 = (int*)(ws + off); off += A((size_t)N2 * CAP1);
    size_t needB = pB + (size_t)N0 * D;  // pre1 words
    if (off < needB) off = needB;
    float* pre1 = ws + pB;

    int* pay_s2 = (int*)(ws + off); off += A((size_t)N0 * CAP2);
    float* pre3 = out;  // d_out doubles as pre3 scratch

    // split-bf16 weight tables (hi/lo), [3][128][128]
    unsigned short* Whi = (unsigned short*)(ws + off); off += A((size_t)3 * D * D / 2);
    unsigned short* Wlo = (unsigned short*)(ws + off); off += A((size_t)3 * D * D / 2);

    // concatenated cursors [d1:N1][d2:N2][d12:N2][s1:N0][s2:N0] (zeroed)
    const int NT = N1 + 2 * N2 + 2 * N0;
    int* cur = (int*)(ws + off); off += A(NT);
    const int cb_d1 = 0, cb_d2 = N1, cb_d12 = N1 + N2;
    const int cb_s1 = N1 + 2 * N2, cb_s2 = N1 + 2 * N2 + N0;

    hipMemsetAsync((void*)cur, 0, (size_t)NT * sizeof(int), stream);

    // x_node -> fp16; W -> split bf16
    long n2 = (long)N0 * D / 2;
    f2h_kernel<<<(n2 + 255) / 256, 256, 0, stream>>>((const float2*)x_node,
                                                     (__half2*)xh, n2);
    wsplit_kernel<<<(3 * D * D + 255) / 256, 256, 0, stream>>>(W1, W2, W12,
                                                               Whi, Wlo);

    // XCD-partitioned ELL fills, one job per dispatch
    FillJob F[5] = {
        {ei1_dst, ei1_src, ew1, pay_d1, cb_d1, CAP1, E1, N1},
        {ei2_dst, ei2_src, ew2, pay_d2, cb_d2, CAP1, E2, N2},
        {ei12_dst, ei12_src, nullptr, pay_d12, cb_d12, CAP2, E12, N2},
        {ei1_src, ei1_dst, nullptr, pay_s1, cb_s1, CAP2, E1, N0},
        {ei2_src, ei2_dst, ew2, pay_s2, cb_s2, CAP2, E2, N0},
    };
    for (int j = 0; j < 5; ++j)
        fill_job_kernel<<<2048, 256, 0, stream>>>(F[j], cur);

    // aggregations
    auto blocks = [](int n) { return (n + 3) / 4; };
    aggh_kernel<true><<<blocks(N1), 256, 0, stream>>>(
        xh, D, cur + cb_d1, CAP1, pay_d1, x1, net1h, D, 0, N1);
    aggh_kernel<true><<<blocks(N2), 256, 0, stream>>>(
        xh, D, cur + cb_d2, CAP1, pay_d2, x2, combo, 2 * D, 0, N2);
    aggh_kernel<false><<<blocks(N2), 256, 0, stream>>>(
        net1h, D, cur + cb_d12, CAP2, pay_d12, x2, combo, 2 * D, D, N2);
    aggf_kernel<<<blocks(N0), 256, 0, stream>>>(net1h, cur + cb_s1, CAP2,
                                                pay_s1, pre1, N0);
    agg2_kernel<<<blocks(N0), 256, 0, stream>>>(combo, cur + cb_s2, CAP2,
                                                pay_s2, pre2, pre3, N0);

    // fused MFMA tail: 3x(linear+relu) + attention (pre3 aliases out)
    mfma_tail_kernel<<<(N0 + 31) / 32, 256, 0, stream>>>(
        pre1, pre2, pre3, Whi, Wlo, b1, b2, b12, att, out, N0);
}

// Round 9
// 928.943 us; speedup vs baseline: 1.0935x; 1.0935x over previous
//
#include <hip/hip_runtime.h>
#include <hip/hip_fp16.h>

#define D 128
#define CAP1 80  // d1, d2 buckets (mean degree 32)
#define CAP2 56  // d12, s1, s2 buckets (mean degree 16)

typedef short s16x8 __attribute__((ext_vector_type(8)));
typedef float f32x4 __attribute__((ext_vector_type(4)));

// ===========================================================================
// ELL fill job descriptor (passed by value, one kernel per job)
// Weighted payloads packed into one int: (idx << 15) | round(w * 32768).
// ===========================================================================
struct FillJob {
    const int* key;    // bucket node id per edge
    const int* other;  // payload index per edge
    const float* w;    // weight (nullptr -> raw index payload)
    int* pay;          // payload at key*cap + slot
    int cbase;         // node base in concatenated cursor space
    int cap;           // bucket capacity
    int E, N;
};

// ===========================================================================
// XCD-partitioned ELL fill, one job per dispatch (stream-serialized).
// ===========================================================================
__global__ __launch_bounds__(256) void fill_job_kernel(FillJob jb,
                                                       int* __restrict__ cursor) {
    int x = blockIdx.x & 7;   // ~XCD id
    int gb = blockIdx.x >> 3; // block index within XCD-group
    int lo = (int)((long)jb.N * x / 8);
    int hi = (int)((long)jb.N * (x + 1) / 8);
    bool hasw = (jb.w != nullptr);
    long stride = (long)(gridDim.x >> 3) * 256;
    for (long e = (long)gb * 256 + threadIdx.x; e < jb.E; e += stride) {
        int key = jb.key[e];
        if (key < lo || key >= hi) continue;
        int pos = atomicAdd(&cursor[jb.cbase + key], 1);
        if (pos >= jb.cap) continue;  // overflow guard (prob ~1e-7 total)
        int o = jb.other[e];
        int v;
        if (hasw) {
            int w15 = __float2int_rn(jb.w[e] * 32768.0f);
            w15 = w15 > 32767 ? 32767 : w15;
            v = (int)(((unsigned)o << 15) | (unsigned)w15);
        } else {
            v = o;
        }
        jb.pay[(long)key * jb.cap + pos] = v;
    }
}

// ===========================================================================
// fp32 -> fp16 conversion (x_node table)
// ===========================================================================
__global__ void f2h_kernel(const float2* __restrict__ in, __half2* __restrict__ o,
                           long n2) {
    long i = (long)blockIdx.x * blockDim.x + threadIdx.x;
    if (i < n2) o[i] = __float22half2_rn(in[i]);
}

// ===========================================================================
// Split W (3 x 128 x 128 fp32) into bf16 hi/lo pair: W = hi + lo + O(2^-16).
// ===========================================================================
__global__ void wsplit_kernel(const float* __restrict__ W1,
                              const float* __restrict__ W2,
                              const float* __restrict__ W12,
                              unsigned short* __restrict__ hi,
                              unsigned short* __restrict__ lo) {
    int i = blockIdx.x * 256 + threadIdx.x;
    if (i >= 3 * D * D) return;
    int p = i >> 14, r = i & (D * D - 1);
    const float* W = p == 0 ? W1 : (p == 1 ? W2 : W12);
    float x = W[r];
    unsigned u = __float_as_uint(x);
    unsigned hb = u & 0xFFFF0000u;
    hi[i] = (unsigned short)(hb >> 16);
    float rem = x - __uint_as_float(hb);
    lo[i] = (unsigned short)(__float_as_uint(rem) >> 16);
}

// ===========================================================================
// Wide-gather aggregation: 16B/lane float4 loads. R1/R2 established these
// kernels are L2-miss-path bound (dur == FETCH/3.1TB/s); lowest-VGPR form.
// ===========================================================================
__device__ __forceinline__ void acc8(float4 raw, float mul, float2 a[4]) {
    const __half2* h = (const __half2*)&raw;
#pragma unroll
    for (int k = 0; k < 4; ++k) {
        float2 f = __half22float2(h[k]);
        a[k].x = fmaf(f.x, mul, a[k].x);
        a[k].y = fmaf(f.y, mul, a[k].y);
    }
}

// Stage-1: gather fp16 rows, fp32 accumulate, combine with fp32 xb,
// write fp16 row at dst[node*dstride + doff]. One wave per node.
template <bool HASW>
__global__ __launch_bounds__(256) void aggh_kernel(
    const __half* __restrict__ vals, int vstride, const int* __restrict__ cnt,
    int cap, const int* __restrict__ pay, const float* __restrict__ xb,
    __half* __restrict__ dst, int dstride, int doff, int N) {
    int node = (int)(((long)blockIdx.x * 256 + threadIdx.x) >> 6);
    int lane = threadIdx.x & 63;
    if (node >= N) return;
    int count = cnt[node];
    int m = count < cap ? count : cap;
    long b0 = (long)node * cap;
    int grp = lane >> 4, il = lane & 15;
    float2 a[4] = {{0.f, 0.f}, {0.f, 0.f}, {0.f, 0.f}, {0.f, 0.f}};
    for (int base = 0; base < m; base += 64) {
        int rem = m - base;
        int n = rem < 64 ? rem : 64;
        int p = 0;
        if (lane < n) p = pay[b0 + base + lane];
        for (int j = 0; j < n; j += 4) {
            int jj = j + grp;
            int pj = __shfl(p, jj, 64);
            int g;
            float wt;
            if (HASW) {
                g = (int)(((unsigned)pj) >> 15);
                wt = (float)(pj & 0x7fff) * (1.0f / 32768.0f);
            } else {
                g = pj;
                wt = 1.0f;
            }
            float mul = jj < n ? wt : 0.0f;
            float4 raw = ((const float4*)(vals + (long)g * vstride))[il];
            acc8(raw, mul, a);
        }
    }
#pragma unroll
    for (int k = 0; k < 4; ++k) {
        a[k].x += __shfl_xor(a[k].x, 16, 64);
        a[k].y += __shfl_xor(a[k].y, 16, 64);
        a[k].x += __shfl_xor(a[k].x, 32, 64);
        a[k].y += __shfl_xor(a[k].y, 32, 64);
    }
    if (lane < 16) {
        float inv = 1.0f / fmaxf((float)count, 1.0f);
        const float4* xp = (const float4*)(xb + (long)node * D + il * 8);
        float4 x0 = xp[0], x1 = xp[1];
        float rx[8] = {x0.x, x0.y, x0.z, x0.w, x1.x, x1.y, x1.z, x1.w};
        __half2 h[4];
#pragma unroll
        for (int k = 0; k < 4; ++k) {
            float2 r;
            r.x = (a[k].x * inv + rx[2 * k + 0]) * 0.5f;
            r.y = (a[k].y * inv + rx[2 * k + 1]) * 0.5f;
            h[k] = __float22half2_rn(r);
        }
        *(float4*)(dst + (long)node * dstride + doff + il * 8) = *(float4*)h;
    }
}

// Stage-2: pre1 = mean over fp16 net1h rows, fp32 output, no combine.
__global__ __launch_bounds__(256) void aggf_kernel(
    const __half* __restrict__ vals, const int* __restrict__ cnt, int cap,
    const int* __restrict__ pay, float* __restrict__ out, int N) {
    int node = (int)(((long)blockIdx.x * 256 + threadIdx.x) >> 6);
    int lane = threadIdx.x & 63;
    if (node >= N) return;
    int count = cnt[node];
    int m = count < cap ? count : cap;
    long b0 = (long)node * cap;
    int grp = lane >> 4, il = lane & 15;
    float2 a[4] = {{0.f, 0.f}, {0.f, 0.f}, {0.f, 0.f}, {0.f, 0.f}};
    for (int base = 0; base < m; base += 64) {
        int rem = m - base;
        int n = rem < 64 ? rem : 64;
        int p = 0;
        if (lane < n) p = pay[b0 + base + lane];
        for (int j = 0; j < n; j += 4) {
            int jj = j + grp;
            int pj = __shfl(p, jj, 64);
            float mul = jj < n ? 1.0f : 0.0f;
            float4 raw = ((const float4*)(vals + (long)pj * D))[il];
            acc8(raw, mul, a);
        }
    }
#pragma unroll
    for (int k = 0; k < 4; ++k) {
        a[k].x += __shfl_xor(a[k].x, 16, 64);
        a[k].y += __shfl_xor(a[k].y, 16, 64);
        a[k].x += __shfl_xor(a[k].x, 32, 64);
        a[k].y += __shfl_xor(a[k].y, 32, 64);
    }
    if (lane < 16) {
        float inv = 1.0f / fmaxf((float)count, 1.0f);
        float4* op = (float4*)(out + (long)node * D + il * 8);
        float4 o0 = {a[0].x * inv, a[0].y * inv, a[1].x * inv, a[1].y * inv};
        float4 o1 = {a[2].x * inv, a[2].y * inv, a[3].x * inv, a[3].y * inv};
        op[0] = o0;
        op[1] = o1;
    }
}

// Fused pre2/pre3: combo rows hold [net2h | net2bh] (256 halves, 512B).
// Requires cap <= 64 (cap = CAP2 = 56): single payload batch.
__global__ __launch_bounds__(256) void agg2_kernel(
    const __half* __restrict__ combo, const int* __restrict__ cnt, int cap,
    const int* __restrict__ pay, float* __restrict__ outa,
    float* __restrict__ outb, int N) {
    int node = (int)(((long)blockIdx.x * 256 + threadIdx.x) >> 6);
    int lane = threadIdx.x & 63;
    if (node >= N) return;
    int count = cnt[node];
    int m = count < cap ? count : cap;
    long b0 = (long)node * cap;
    int grp = lane >> 5, il = lane & 31;
    float2 a[4] = {{0.f, 0.f}, {0.f, 0.f}, {0.f, 0.f}, {0.f, 0.f}};
    int p = 0;
    if (lane < m) p = pay[b0 + lane];
    for (int j = 0; j < m; j += 2) {
        int jj = j + grp;
        int pj = __shfl(p, jj, 64);
        int g = (int)(((unsigned)pj) >> 15);
        float w = (float)(pj & 0x7fff) * (1.0f / 32768.0f);
        float mul = jj < m ? (il < 16 ? 1.0f : w) : 0.0f;
        float4 raw = ((const float4*)(combo + (long)g * 256))[il];
        acc8(raw, mul, a);
    }
#pragma unroll
    for (int k = 0; k < 4; ++k) {
        a[k].x += __shfl_xor(a[k].x, 32, 64);
        a[k].y += __shfl_xor(a[k].y, 32, 64);
    }
    if (lane < 32) {
        float inv = 1.0f / fmaxf((float)count, 1.0f);
        float* o = (il < 16) ? (outa + (long)node * D + il * 8)
                             : (outb + (long)node * D + (il - 16) * 8);
        float4 o0 = {a[0].x * inv, a[0].y * inv, a[1].x * inv, a[1].y * inv};
        float4 o1 = {a[2].x * inv, a[2].y * inv, a[3].x * inv, a[3].y * inv};
        ((float4*)o)[0] = o0;
        ((float4*)o)[1] = o1;
    }
}

// ===========================================================================
// MFMA tail v3b: out = attn(relu(pre_p @ Wp^T + bp)) via split-bf16 MFMA.
// R7 PMC: occupancy 10->46% with no speedup -> limiter is per-wave
// just-in-time W streaming from L2 (~1.2 GB at the ~7 TB/s latency ceiling).
// v3b stages W in LDS once per block. R8 lesson: v3's 69,632 B static LDS
// exceeded the 64 KB workgroup limit (launch failure) -> v3b uses EXACTLY
// 65,536 B with an XOR swizzle instead of row padding: 16B slot s of row r
// lives at r*256 + ((s ^ (r&7))*16). Read groups (rows c*16+rw, slot
// kt*4+kg) then spread uniformly over all 8 bank-groups -> conflict-free.
// Block = 512 threads (8 waves) x 128 rows; per path p: stage Wp hi+lo
// (64 KB total), sync, MFMA from LDS, sync.
// pre3 aliases out: all pre3 reads in the p=2 phase, stores after; blocks
// row-disjoint -> safe.
// ===========================================================================
#define LO_OFF 32768  // lo table offset in wlds

__device__ __forceinline__ int wswz(int r, int s) {
    return r * 256 + ((s ^ (r & 7)) << 4);
}

__global__ __launch_bounds__(512, 2) void mfma_tail_kernel(
    const float* __restrict__ pre1, const float* __restrict__ pre2,
    const float* pre3, const unsigned short* __restrict__ Whi,
    const unsigned short* __restrict__ Wlo, const float* __restrict__ b1,
    const float* __restrict__ b2, const float* __restrict__ b12,
    const float* __restrict__ att, float* out, int N) {
    __shared__ __align__(16) char wlds[2 * 128 * 256];  // 65536 B: hi | lo
    int tid = threadIdx.x;
    int wv = tid >> 6, lane = tid & 63;
    int rw = lane & 15, kg = lane >> 4;
    int m0 = blockIdx.x * 128 + wv * 16;
    int mrow = m0 + rw;
    if (mrow >= N) mrow = N - 1;  // clamp; no early return (barriers below)
    const float* PRE[3] = {pre1, pre2, pre3};
    const float* BB[3] = {b1, b2, b12};

    f32x4 acc[3][8];
#pragma unroll
    for (int p = 0; p < 3; ++p)
#pragma unroll
        for (int c = 0; c < 8; ++c) acc[p][c] = (f32x4){0.f, 0.f, 0.f, 0.f};

    for (int p = 0; p < 3; ++p) {
        // ---- stage Wp (hi+lo) into LDS: 2048 16B-chunks each, swizzled ----
        const unsigned short* WH = Whi + ((long)p << 14);
        const unsigned short* WL = Wlo + ((long)p << 14);
#pragma unroll
        for (int c = 0; c < 4; ++c) {
            int idx = tid + c * 512;      // 0..2047
            int r = idx >> 4, s = idx & 15;
            int dst = wswz(r, s);
            *(float4*)(wlds + dst) = *(const float4*)(WH + r * D + s * 8);
            *(float4*)(wlds + LO_OFF + dst) =
                *(const float4*)(WL + r * D + s * 8);
        }
        __syncthreads();

        // ---- compute: 4 k-steps x 8 col-tiles, B-fragments from LDS ----
        const float* src = PRE[p] + (long)mrow * D + kg * 8;
#pragma unroll
        for (int kt = 0; kt < 4; ++kt) {
            float4 xa = *(const float4*)(src + kt * 32);
            float4 xb = *(const float4*)(src + kt * 32 + 4);
            float xs[8] = {xa.x, xa.y, xa.z, xa.w, xb.x, xb.y, xb.z, xb.w};
            s16x8 ah, al;
#pragma unroll
            for (int i = 0; i < 8; ++i) {
                unsigned u = __float_as_uint(xs[i]);
                unsigned hb = u & 0xFFFF0000u;
                ah[i] = (short)(hb >> 16);
                float rem = xs[i] - __uint_as_float(hb);
                al[i] = (short)(__float_as_uint(rem) >> 16);
            }
#pragma unroll
            for (int c = 0; c < 8; ++c) {
                // B row = c*16 + rw, 16B slot = kt*4 + kg (swizzled)
                const char* bp = wlds + wswz(c * 16 + rw, kt * 4 + kg);
                s16x8 bh = *(const s16x8*)bp;
                s16x8 bl = *(const s16x8*)(bp + LO_OFF);
                acc[p][c] = __builtin_amdgcn_mfma_f32_16x16x32_bf16(
                    ah, bh, acc[p][c], 0, 0, 0);
                acc[p][c] = __builtin_amdgcn_mfma_f32_16x16x32_bf16(
                    ah, bl, acc[p][c], 0, 0, 0);
                acc[p][c] = __builtin_amdgcn_mfma_f32_16x16x32_bf16(
                    al, bh, acc[p][c], 0, 0, 0);
            }
        }
        __syncthreads();  // protect LDS before next path's staging
    }

    // bias + relu (in place) + per-row attention partial dots
    float sc[3][4] = {{0.f, 0.f, 0.f, 0.f},
                      {0.f, 0.f, 0.f, 0.f},
                      {0.f, 0.f, 0.f, 0.f}};
#pragma unroll
    for (int p = 0; p < 3; ++p) {
#pragma unroll
        for (int c = 0; c < 8; ++c) {
            float bv = BB[p][c * 16 + rw];
            float av = att[p * D + c * 16 + rw];
#pragma unroll
            for (int j = 0; j < 4; ++j) {
                float v = fmaxf(acc[p][c][j] + bv, 0.0f);
                acc[p][c][j] = v;
                sc[p][j] = fmaf(v, av, sc[p][j]);
            }
        }
    }
    // reduce scores across the 16 lanes sharing a row set (xor 1,2,4,8)
#pragma unroll
    for (int j = 0; j < 4; ++j) {
#pragma unroll
        for (int off = 1; off < 16; off <<= 1) {
            sc[0][j] += __shfl_xor(sc[0][j], off, 64);
            sc[1][j] += __shfl_xor(sc[1][j], off, 64);
            sc[2][j] += __shfl_xor(sc[2][j], off, 64);
        }
    }
    // softmax + blend + store; row = m0 + kg*4 + j, col = c*16 + rw
#pragma unroll
    for (int j = 0; j < 4; ++j) {
        float s0 = sc[0][j], s1 = sc[1][j], s2 = sc[2][j];
        float mx = fmaxf(s0, fmaxf(s1, s2));
        float e0 = __expf(s0 - mx), e1 = __expf(s1 - mx), e2 = __expf(s2 - mx);
        float inv = 1.0f / (e0 + e1 + e2);
        float w0 = e0 * inv, w1 = e1 * inv, w2 = e2 * inv;
        int orow = m0 + kg * 4 + j;
        if (orow < N) {
            long ro = (long)orow * D + rw;
#pragma unroll
            for (int c = 0; c < 8; ++c) {
                out[ro + c * 16] =
                    acc[0][c][j] * w0 + acc[1][c][j] * w1 + acc[2][c][j] * w2;
            }
        }
    }
}

// ===========================================================================
extern "C" void kernel_launch(void* const* d_in, const int* in_sizes, int n_in,
                              void* d_out, int out_size, void* d_ws,
                              size_t ws_size, hipStream_t stream) {
    const float* x_node = (const float*)d_in[0];
    const float* x1 = (const float*)d_in[1];
    const float* x2 = (const float*)d_in[2];
    const int* ei1_src = (const int*)d_in[3];
    const int* ei1_dst = (const int*)d_in[4];
    const int* ei2_src = (const int*)d_in[5];
    const int* ei2_dst = (const int*)d_in[6];
    const int* ei12_src = (const int*)d_in[7];
    const int* ei12_dst = (const int*)d_in[8];
    const float* ew1 = (const float*)d_in[9];
    const float* ew2 = (const float*)d_in[10];
    const float* W1 = (const float*)d_in[11];
    const float* b1 = (const float*)d_in[12];
    const float* W2 = (const float*)d_in[13];
    const float* b2 = (const float*)d_in[14];
    const float* W12 = (const float*)d_in[15];
    const float* b12 = (const float*)d_in[16];
    const float* att = (const float*)d_in[17];
    float* out = (float*)d_out;

    const int N0 = in_sizes[0] / D;
    const int N1 = in_sizes[1] / D;
    const int N2 = in_sizes[2] / D;
    const int E1 = in_sizes[3];
    const int E2 = in_sizes[5];
    const int E12 = in_sizes[7];

    float* ws = (float*)d_ws;
    size_t off = 0;
    auto A = [](size_t v) { return (v + 3) & ~(size_t)3; };  // 16B align (words)

    // fp16 tables
    __half* xh = (__half*)(ws + off);    off += A((size_t)N0 * D / 2);
    __half* net1h = (__half*)(ws + off); off += A((size_t)N1 * D / 2);
    __half* combo = (__half*)(ws + off); off += A((size_t)N2 * D);  // 256 h/row

    // --- ELL payload block A: pay_d12, pay_s1 (dead after aggf) ---
    // pre2 aliases this block (written by agg2, after both are dead).
    size_t pA = off;
    int* pay_d12 = (int*)(ws + off); off += A((size_t)N2 * CAP2);
    int* pay_s1 = (int*)(ws + off);  off += A((size_t)N0 * CAP2);
    size_t needA = pA + (size_t)N0 * D;  // pre2 words
    if (off < needA) off = needA;
    float* pre2 = ws + pA;

    // --- ELL payload block B: pay_d1, pay_d2 (dead after aggh d1/d2) ---
    // pre1 aliases this block (written by aggf, after both are dead).
    size_t pB = off;
    int* pay_d1 = (int*)(ws + off); off += A((size_t)N1 * CAP1);
    int* pay_d2 = (int*)(ws + off); off += A((size_t)N2 * CAP1);
    size_t needB = pB + (size_t)N0 * D;  // pre1 words
    if (off < needB) off = needB;
    float* pre1 = ws + pB;

    int* pay_s2 = (int*)(ws + off); off += A((size_t)N0 * CAP2);
    float* pre3 = out;  // d_out doubles as pre3 scratch

    // split-bf16 weight tables (hi/lo), [3][128][128]
    unsigned short* Whi = (unsigned short*)(ws + off); off += A((size_t)3 * D * D / 2);
    unsigned short* Wlo = (unsigned short*)(ws + off); off += A((size_t)3 * D * D / 2);

    // concatenated cursors [d1:N1][d2:N2][d12:N2][s1:N0][s2:N0] (zeroed)
    const int NT = N1 + 2 * N2 + 2 * N0;
    int* cur = (int*)(ws + off); off += A(NT);
    const int cb_d1 = 0, cb_d2 = N1, cb_d12 = N1 + N2;
    const int cb_s1 = N1 + 2 * N2, cb_s2 = N1 + 2 * N2 + N0;

    hipMemsetAsync((void*)cur, 0, (size_t)NT * sizeof(int), stream);

    // x_node -> fp16; W -> split bf16
    long n2 = (long)N0 * D / 2;
    f2h_kernel<<<(n2 + 255) / 256, 256, 0, stream>>>((const float2*)x_node,
                                                     (__half2*)xh, n2);
    wsplit_kernel<<<(3 * D * D + 255) / 256, 256, 0, stream>>>(W1, W2, W12,
                                                               Whi, Wlo);

    // XCD-partitioned ELL fills, one job per dispatch
    FillJob F[5] = {
        {ei1_dst, ei1_src, ew1, pay_d1, cb_d1, CAP1, E1, N1},
        {ei2_dst, ei2_src, ew2, pay_d2, cb_d2, CAP1, E2, N2},
        {ei12_dst, ei12_src, nullptr, pay_d12, cb_d12, CAP2, E12, N2},
        {ei1_src, ei1_dst, nullptr, pay_s1, cb_s1, CAP2, E1, N0},
        {ei2_src, ei2_dst, ew2, pay_s2, cb_s2, CAP2, E2, N0},
    };
    for (int j = 0; j < 5; ++j)
        fill_job_kernel<<<2048, 256, 0, stream>>>(F[j], cur);

    // aggregations
    auto blocks = [](int n) { return (n + 3) / 4; };
    aggh_kernel<true><<<blocks(N1), 256, 0, stream>>>(
        xh, D, cur + cb_d1, CAP1, pay_d1, x1, net1h, D, 0, N1);
    aggh_kernel<true><<<blocks(N2), 256, 0, stream>>>(
        xh, D, cur + cb_d2, CAP1, pay_d2, x2, combo, 2 * D, 0, N2);
    aggh_kernel<false><<<blocks(N2), 256, 0, stream>>>(
        net1h, D, cur + cb_d12, CAP2, pay_d12, x2, combo, 2 * D, D, N2);
    aggf_kernel<<<blocks(N0), 256, 0, stream>>>(net1h, cur + cb_s1, CAP2,
                                                pay_s1, pre1, N0);
    agg2_kernel<<<blocks(N0), 256, 0, stream>>>(combo, cur + cb_s2, CAP2,
                                                pay_s2, pre2, pre3, N0);

    // fused MFMA tail: 3x(linear+relu) + attention (pre3 aliases out)
    mfma_tail_kernel<<<(N0 + 127) / 128, 512, 0, stream>>>(
        pre1, pre2, pre3, Whi, Wlo, b1, b2, b12, att, out, N0);
}

// Round 10
// 892.638 us; speedup vs baseline: 1.1379x; 1.0407x over previous
//
#include <hip/hip_runtime.h>
#include <hip/hip_fp16.h>

#define D 128
#define CAP1 80  // d1, d2 buckets (mean degree 32)
#define CAP2 56  // d12, s1, s2 buckets (mean degree 16)

typedef short s16x8 __attribute__((ext_vector_type(8)));
typedef float f32x4 __attribute__((ext_vector_type(4)));

// ===========================================================================
// ELL fill job descriptor. Weighted payloads packed into one int:
// (idx << 15) | round(w * 32768).
// ===========================================================================
struct FillJob {
    const int* key;    // bucket node id per edge
    const int* other;  // payload index per edge
    const float* w;    // weight (nullptr -> raw index payload)
    int* pay;          // payload at key*cap + slot
    int cbase;         // node base in concatenated cursor space
    int cap;           // bucket capacity
    int E, N;
};
struct FillJobs2 { FillJob j[2]; };

// ===========================================================================
// XCD-partitioned ELL fill, PAIRED jobs (blockIdx.y), 3 dispatches total.
// Blocks round-robin over 8 XCDs (blockIdx.x & 7; x fastest in dispatch
// order and gridDim.x % 8 == 0 keeps the mapping under 2D grids); each
// XCD-group owns key range [N*x/8, N*(x+1)/8). Pairs chosen so combined
// per-XCD write windows stay ~<= 4 MB L2: {d1,d2}=4.0, {d12,s1}=4.2,
// {s2}=2.8. grid.x = 4096 (2 blocks/CU per XCD-group) for TLP against
// ~700cy L3 key-load latency (R5 PMC: VALUBusy 8.7% -> latency-bound).
// ===========================================================================
__global__ __launch_bounds__(256) void fill_pair_kernel(FillJobs2 J,
                                                        int* __restrict__ cursor) {
    FillJob jb = J.j[blockIdx.y];
    int x = blockIdx.x & 7;   // ~XCD id
    int gb = blockIdx.x >> 3; // block index within XCD-group
    int lo = (int)((long)jb.N * x / 8);
    int hi = (int)((long)jb.N * (x + 1) / 8);
    bool hasw = (jb.w != nullptr);
    long stride = (long)(gridDim.x >> 3) * 256;
    for (long e = (long)gb * 256 + threadIdx.x; e < jb.E; e += stride) {
        int key = jb.key[e];
        if (key < lo || key >= hi) continue;
        int pos = atomicAdd(&cursor[jb.cbase + key], 1);
        if (pos >= jb.cap) continue;  // overflow guard (prob ~1e-7 total)
        int o = jb.other[e];
        int v;
        if (hasw) {
            int w15 = __float2int_rn(jb.w[e] * 32768.0f);
            w15 = w15 > 32767 ? 32767 : w15;
            v = (int)(((unsigned)o << 15) | (unsigned)w15);
        } else {
            v = o;
        }
        jb.pay[(long)key * jb.cap + pos] = v;
    }
}

// ===========================================================================
// fp32 -> fp16 conversion (x_node table)
// ===========================================================================
__global__ void f2h_kernel(const float2* __restrict__ in, __half2* __restrict__ o,
                           long n2) {
    long i = (long)blockIdx.x * blockDim.x + threadIdx.x;
    if (i < n2) o[i] = __float22half2_rn(in[i]);
}

// ===========================================================================
// Split W (3 x 128 x 128 fp32) into bf16 hi/lo pair: W = hi + lo + O(2^-16).
// ===========================================================================
__global__ void wsplit_kernel(const float* __restrict__ W1,
                              const float* __restrict__ W2,
                              const float* __restrict__ W12,
                              unsigned short* __restrict__ hi,
                              unsigned short* __restrict__ lo) {
    int i = blockIdx.x * 256 + threadIdx.x;
    if (i >= 3 * D * D) return;
    int p = i >> 14, r = i & (D * D - 1);
    const float* W = p == 0 ? W1 : (p == 1 ? W2 : W12);
    float x = W[r];
    unsigned u = __float_as_uint(x);
    unsigned hb = u & 0xFFFF0000u;
    hi[i] = (unsigned short)(hb >> 16);
    float rem = x - __uint_as_float(hb);
    lo[i] = (unsigned short)(__float_as_uint(rem) >> 16);
}

// ===========================================================================
// Wide-gather aggregation: 16B/lane float4 loads. R1/R2 established these
// kernels are L2-miss-path bound (dur == FETCH/3.1TB/s); lowest-VGPR form.
// ===========================================================================
__device__ __forceinline__ void acc8(float4 raw, float mul, float2 a[4]) {
    const __half2* h = (const __half2*)&raw;
#pragma unroll
    for (int k = 0; k < 4; ++k) {
        float2 f = __half22float2(h[k]);
        a[k].x = fmaf(f.x, mul, a[k].x);
        a[k].y = fmaf(f.y, mul, a[k].y);
    }
}

// Stage-1: gather fp16 rows, fp32 accumulate, combine with fp32 xb,
// write fp16 row at dst[node*dstride + doff]. One wave per node.
template <bool HASW>
__global__ __launch_bounds__(256) void aggh_kernel(
    const __half* __restrict__ vals, int vstride, const int* __restrict__ cnt,
    int cap, const int* __restrict__ pay, const float* __restrict__ xb,
    __half* __restrict__ dst, int dstride, int doff, int N) {
    int node = (int)(((long)blockIdx.x * 256 + threadIdx.x) >> 6);
    int lane = threadIdx.x & 63;
    if (node >= N) return;
    int count = cnt[node];
    int m = count < cap ? count : cap;
    long b0 = (long)node * cap;
    int grp = lane >> 4, il = lane & 15;
    float2 a[4] = {{0.f, 0.f}, {0.f, 0.f}, {0.f, 0.f}, {0.f, 0.f}};
    for (int base = 0; base < m; base += 64) {
        int rem = m - base;
        int n = rem < 64 ? rem : 64;
        int p = 0;
        if (lane < n) p = pay[b0 + base + lane];
        for (int j = 0; j < n; j += 4) {
            int jj = j + grp;
            int pj = __shfl(p, jj, 64);
            int g;
            float wt;
            if (HASW) {
                g = (int)(((unsigned)pj) >> 15);
                wt = (float)(pj & 0x7fff) * (1.0f / 32768.0f);
            } else {
                g = pj;
                wt = 1.0f;
            }
            float mul = jj < n ? wt : 0.0f;
            float4 raw = ((const float4*)(vals + (long)g * vstride))[il];
            acc8(raw, mul, a);
        }
    }
#pragma unroll
    for (int k = 0; k < 4; ++k) {
        a[k].x += __shfl_xor(a[k].x, 16, 64);
        a[k].y += __shfl_xor(a[k].y, 16, 64);
        a[k].x += __shfl_xor(a[k].x, 32, 64);
        a[k].y += __shfl_xor(a[k].y, 32, 64);
    }
    if (lane < 16) {
        float inv = 1.0f / fmaxf((float)count, 1.0f);
        const float4* xp = (const float4*)(xb + (long)node * D + il * 8);
        float4 x0 = xp[0], x1 = xp[1];
        float rx[8] = {x0.x, x0.y, x0.z, x0.w, x1.x, x1.y, x1.z, x1.w};
        __half2 h[4];
#pragma unroll
        for (int k = 0; k < 4; ++k) {
            float2 r;
            r.x = (a[k].x * inv + rx[2 * k + 0]) * 0.5f;
            r.y = (a[k].y * inv + rx[2 * k + 1]) * 0.5f;
            h[k] = __float22half2_rn(r);
        }
        *(float4*)(dst + (long)node * dstride + doff + il * 8) = *(float4*)h;
    }
}

// Stage-2: pre1 = mean over fp16 net1h rows, fp32 output, no combine.
__global__ __launch_bounds__(256) void aggf_kernel(
    const __half* __restrict__ vals, const int* __restrict__ cnt, int cap,
    const int* __restrict__ pay, float* __restrict__ out, int N) {
    int node = (int)(((long)blockIdx.x * 256 + threadIdx.x) >> 6);
    int lane = threadIdx.x & 63;
    if (node >= N) return;
    int count = cnt[node];
    int m = count < cap ? count : cap;
    long b0 = (long)node * cap;
    int grp = lane >> 4, il = lane & 15;
    float2 a[4] = {{0.f, 0.f}, {0.f, 0.f}, {0.f, 0.f}, {0.f, 0.f}};
    for (int base = 0; base < m; base += 64) {
        int rem = m - base;
        int n = rem < 64 ? rem : 64;
        int p = 0;
        if (lane < n) p = pay[b0 + base + lane];
        for (int j = 0; j < n; j += 4) {
            int jj = j + grp;
            int pj = __shfl(p, jj, 64);
            float mul = jj < n ? 1.0f : 0.0f;
            float4 raw = ((const float4*)(vals + (long)pj * D))[il];
            acc8(raw, mul, a);
        }
    }
#pragma unroll
    for (int k = 0; k < 4; ++k) {
        a[k].x += __shfl_xor(a[k].x, 16, 64);
        a[k].y += __shfl_xor(a[k].y, 16, 64);
        a[k].x += __shfl_xor(a[k].x, 32, 64);
        a[k].y += __shfl_xor(a[k].y, 32, 64);
    }
    if (lane < 16) {
        float inv = 1.0f / fmaxf((float)count, 1.0f);
        float4* op = (float4*)(out + (long)node * D + il * 8);
        float4 o0 = {a[0].x * inv, a[0].y * inv, a[1].x * inv, a[1].y * inv};
        float4 o1 = {a[2].x * inv, a[2].y * inv, a[3].x * inv, a[3].y * inv};
        op[0] = o0;
        op[1] = o1;
    }
}

// Fused pre2/pre3: combo rows hold [net2h | net2bh] (256 halves, 512B).
// Requires cap <= 64 (cap = CAP2 = 56): single payload batch.
__global__ __launch_bounds__(256) void agg2_kernel(
    const __half* __restrict__ combo, const int* __restrict__ cnt, int cap,
    const int* __restrict__ pay, float* __restrict__ outa,
    float* __restrict__ outb, int N) {
    int node = (int)(((long)blockIdx.x * 256 + threadIdx.x) >> 6);
    int lane = threadIdx.x & 63;
    if (node >= N) return;
    int count = cnt[node];
    int m = count < cap ? count : cap;
    long b0 = (long)node * cap;
    int grp = lane >> 5, il = lane & 31;
    float2 a[4] = {{0.f, 0.f}, {0.f, 0.f}, {0.f, 0.f}, {0.f, 0.f}};
    int p = 0;
    if (lane < m) p = pay[b0 + lane];
    for (int j = 0; j < m; j += 2) {
        int jj = j + grp;
        int pj = __shfl(p, jj, 64);
        int g = (int)(((unsigned)pj) >> 15);
        float w = (float)(pj & 0x7fff) * (1.0f / 32768.0f);
        float mul = jj < m ? (il < 16 ? 1.0f : w) : 0.0f;
        float4 raw = ((const float4*)(combo + (long)g * 256))[il];
        acc8(raw, mul, a);
    }
#pragma unroll
    for (int k = 0; k < 4; ++k) {
        a[k].x += __shfl_xor(a[k].x, 32, 64);
        a[k].y += __shfl_xor(a[k].y, 32, 64);
    }
    if (lane < 32) {
        float inv = 1.0f / fmaxf((float)count, 1.0f);
        float* o = (il < 16) ? (outa + (long)node * D + il * 8)
                             : (outb + (long)node * D + (il - 16) * 8);
        float4 o0 = {a[0].x * inv, a[0].y * inv, a[1].x * inv, a[1].y * inv};
        float4 o1 = {a[2].x * inv, a[2].y * inv, a[3].x * inv, a[3].y * inv};
        ((float4*)o)[0] = o0;
        ((float4*)o)[1] = o1;
    }
}

// ===========================================================================
// MFMA tail v4: out = attn(relu(pre_p @ Wp^T + bp)) via split-bf16 MFMA,
// LDS-staged W (v3b) + 16x64 per-wave tile (v2). v3b ran at 1 block/CU
// (VGPR ~136 -> 12 waves/CU < 16) so staging/pre-load latency had no
// cross-block overlap. v4: acc 96->48 VGPR (~100 total) -> 2 blocks/CU;
// block = 512 threads = 4 row-strips x 2 col-halves over 64 rows.
// Cross-half attention scores combine via sred aliased into wlds after the
// final compute sync (no extra LDS; stays at the 65,536 B limit).
// pre3 aliases out: reads in p=2 phase, stores after; blocks row-disjoint.
// ===========================================================================
#define LO_OFF 32768  // lo table offset in wlds

__device__ __forceinline__ int wswz(int r, int s) {
    return r * 256 + ((s ^ (r & 7)) << 4);
}

__global__ __launch_bounds__(512, 2) void mfma_tail_kernel(
    const float* __restrict__ pre1, const float* __restrict__ pre2,
    const float* pre3, const unsigned short* __restrict__ Whi,
    const unsigned short* __restrict__ Wlo, const float* __restrict__ b1,
    const float* __restrict__ b2, const float* __restrict__ b12,
    const float* __restrict__ att, float* out, int N) {
    __shared__ __align__(16) char wlds[2 * 128 * 256];  // 65536 B: hi | lo
    int tid = threadIdx.x;
    int wv = tid >> 6, lane = tid & 63;
    int strip = wv >> 1, half = wv & 1;
    int rw = lane & 15, kg = lane >> 4;
    int m0 = blockIdx.x * 64 + strip * 16;
    int mrow = m0 + rw;
    if (mrow >= N) mrow = N - 1;  // clamp; no early return (barriers below)
    const float* PRE[3] = {pre1, pre2, pre3};
    const float* BB[3] = {b1, b2, b12};

    f32x4 acc[3][4];
#pragma unroll
    for (int p = 0; p < 3; ++p)
#pragma unroll
        for (int c = 0; c < 4; ++c) acc[p][c] = (f32x4){0.f, 0.f, 0.f, 0.f};

    for (int p = 0; p < 3; ++p) {
        // ---- stage Wp (hi+lo) into LDS: 2048 16B-chunks each, swizzled ----
        const unsigned short* WH = Whi + ((long)p << 14);
        const unsigned short* WL = Wlo + ((long)p << 14);
#pragma unroll
        for (int c = 0; c < 4; ++c) {
            int idx = tid + c * 512;      // 0..2047
            int r = idx >> 4, s = idx & 15;
            int dst = wswz(r, s);
            *(float4*)(wlds + dst) = *(const float4*)(WH + r * D + s * 8);
            *(float4*)(wlds + LO_OFF + dst) =
                *(const float4*)(WL + r * D + s * 8);
        }
        __syncthreads();

        // ---- compute: 4 k-steps x 4 col-tiles (own 64-col half) ----
        const float* src = PRE[p] + (long)mrow * D + kg * 8;
#pragma unroll
        for (int kt = 0; kt < 4; ++kt) {
            float4 xa = *(const float4*)(src + kt * 32);
            float4 xb = *(const float4*)(src + kt * 32 + 4);
            float xs[8] = {xa.x, xa.y, xa.z, xa.w, xb.x, xb.y, xb.z, xb.w};
            s16x8 ah, al;
#pragma unroll
            for (int i = 0; i < 8; ++i) {
                unsigned u = __float_as_uint(xs[i]);
                unsigned hb = u & 0xFFFF0000u;
                ah[i] = (short)(hb >> 16);
                float rem = xs[i] - __uint_as_float(hb);
                al[i] = (short)(__float_as_uint(rem) >> 16);
            }
#pragma unroll
            for (int c = 0; c < 4; ++c) {
                // B row = half*64 + c*16 + rw, 16B slot = kt*4 + kg
                const char* bp =
                    wlds + wswz(half * 64 + c * 16 + rw, kt * 4 + kg);
                s16x8 bh = *(const s16x8*)bp;
                s16x8 bl = *(const s16x8*)(bp + LO_OFF);
                acc[p][c] = __builtin_amdgcn_mfma_f32_16x16x32_bf16(
                    ah, bh, acc[p][c], 0, 0, 0);
                acc[p][c] = __builtin_amdgcn_mfma_f32_16x16x32_bf16(
                    ah, bl, acc[p][c], 0, 0, 0);
                acc[p][c] = __builtin_amdgcn_mfma_f32_16x16x32_bf16(
                    al, bh, acc[p][c], 0, 0, 0);
            }
        }
        __syncthreads();  // protect LDS before next path's staging / sred
    }

    // bias + relu (in place) + half-row attention partial dots
    float sc[3][4] = {{0.f, 0.f, 0.f, 0.f},
                      {0.f, 0.f, 0.f, 0.f},
                      {0.f, 0.f, 0.f, 0.f}};
#pragma unroll
    for (int p = 0; p < 3; ++p) {
#pragma unroll
        for (int c = 0; c < 4; ++c) {
            int col = half * 64 + c * 16 + rw;
            float bv = BB[p][col];
            float av = att[p * D + col];
#pragma unroll
            for (int j = 0; j < 4; ++j) {
                float v = fmaxf(acc[p][c][j] + bv, 0.0f);
                acc[p][c][j] = v;
                sc[p][j] = fmaf(v, av, sc[p][j]);
            }
        }
    }
    // reduce within 16-lane groups (rows kg*4+j)
#pragma unroll
    for (int j = 0; j < 4; ++j) {
#pragma unroll
        for (int off = 1; off < 16; off <<= 1) {
            sc[0][j] += __shfl_xor(sc[0][j], off, 64);
            sc[1][j] += __shfl_xor(sc[1][j], off, 64);
            sc[2][j] += __shfl_xor(sc[2][j], off, 64);
        }
    }
    // publish half-row sums via sred aliased into wlds (ordered by the
    // syncthreads above/below); layout [strip][half][path][row16]
    float* sred = (float*)wlds;
    if (rw == 0) {
#pragma unroll
        for (int p = 0; p < 3; ++p)
#pragma unroll
            for (int j = 0; j < 4; ++j)
                sred[((strip * 2 + half) * 3 + p) * 16 + kg * 4 + j] = sc[p][j];
    }
    __syncthreads();

    // combine halves, softmax, blend, store (own 64-col half)
#pragma unroll
    for (int j = 0; j < 4; ++j) {
        int row = kg * 4 + j;
        float s0 = sred[((strip * 2 + 0) * 3 + 0) * 16 + row] +
                   sred[((strip * 2 + 1) * 3 + 0) * 16 + row];
        float s1 = sred[((strip * 2 + 0) * 3 + 1) * 16 + row] +
                   sred[((strip * 2 + 1) * 3 + 1) * 16 + row];
        float s2 = sred[((strip * 2 + 0) * 3 + 2) * 16 + row] +
                   sred[((strip * 2 + 1) * 3 + 2) * 16 + row];
        float mx = fmaxf(s0, fmaxf(s1, s2));
        float e0 = __expf(s0 - mx), e1 = __expf(s1 - mx), e2 = __expf(s2 - mx);
        float inv = 1.0f / (e0 + e1 + e2);
        float w0 = e0 * inv, w1 = e1 * inv, w2 = e2 * inv;
        int orow = m0 + row;
        if (orow < N) {
            long ro = (long)orow * D + half * 64 + rw;
#pragma unroll
            for (int c = 0; c < 4; ++c) {
                out[ro + c * 16] =
                    acc[0][c][j] * w0 + acc[1][c][j] * w1 + acc[2][c][j] * w2;
            }
        }
    }
}

// ===========================================================================
extern "C" void kernel_launch(void* const* d_in, const int* in_sizes, int n_in,
                              void* d_out, int out_size, void* d_ws,
                              size_t ws_size, hipStream_t stream) {
    const float* x_node = (const float*)d_in[0];
    const float* x1 = (const float*)d_in[1];
    const float* x2 = (const float*)d_in[2];
    const int* ei1_src = (const int*)d_in[3];
    const int* ei1_dst = (const int*)d_in[4];
    const int* ei2_src = (const int*)d_in[5];
    const int* ei2_dst = (const int*)d_in[6];
    const int* ei12_src = (const int*)d_in[7];
    const int* ei12_dst = (const int*)d_in[8];
    const float* ew1 = (const float*)d_in[9];
    const float* ew2 = (const float*)d_in[10];
    const float* W1 = (const float*)d_in[11];
    const float* b1 = (const float*)d_in[12];
    const float* W2 = (const float*)d_in[13];
    const float* b2 = (const float*)d_in[14];
    const float* W12 = (const float*)d_in[15];
    const float* b12 = (const float*)d_in[16];
    const float* att = (const float*)d_in[17];
    float* out = (float*)d_out;

    const int N0 = in_sizes[0] / D;
    const int N1 = in_sizes[1] / D;
    const int N2 = in_sizes[2] / D;
    const int E1 = in_sizes[3];
    const int E2 = in_sizes[5];
    const int E12 = in_sizes[7];

    float* ws = (float*)d_ws;
    size_t off = 0;
    auto A = [](size_t v) { return (v + 3) & ~(size_t)3; };  // 16B align (words)

    // fp16 tables
    __half* xh = (__half*)(ws + off);    off += A((size_t)N0 * D / 2);
    __half* net1h = (__half*)(ws + off); off += A((size_t)N1 * D / 2);
    __half* combo = (__half*)(ws + off); off += A((size_t)N2 * D);  // 256 h/row

    // --- ELL payload block A: pay_d12, pay_s1 (dead after aggf) ---
    // pre2 aliases this block (written by agg2, after both are dead).
    size_t pA = off;
    int* pay_d12 = (int*)(ws + off); off += A((size_t)N2 * CAP2);
    int* pay_s1 = (int*)(ws + off);  off += A((size_t)N0 * CAP2);
    size_t needA = pA + (size_t)N0 * D;  // pre2 words
    if (off < needA) off = needA;
    float* pre2 = ws + pA;

    // --- ELL payload block B: pay_d1, pay_d2 (dead after aggh d1/d2) ---
    // pre1 aliases this block (written by aggf, after both are dead).
    size_t pB = off;
    int* pay_d1 = (int*)(ws + off); off += A((size_t)N1 * CAP1);
    int* pay_d2 = (int*)(ws + off); off += A((size_t)N2 * CAP1);
    size_t needB = pB + (size_t)N0 * D;  // pre1 words
    if (off < needB) off = needB;
    float* pre1 = ws + pB;

    int* pay_s2 = (int*)(ws + off); off += A((size_t)N0 * CAP2);
    float* pre3 = out;  // d_out doubles as pre3 scratch

    // split-bf16 weight tables (hi/lo), [3][128][128]
    unsigned short* Whi = (unsigned short*)(ws + off); off += A((size_t)3 * D * D / 2);
    unsigned short* Wlo = (unsigned short*)(ws + off); off += A((size_t)3 * D * D / 2);

    // concatenated cursors [d1:N1][d2:N2][d12:N2][s1:N0][s2:N0] (zeroed)
    const int NT = N1 + 2 * N2 + 2 * N0;
    int* cur = (int*)(ws + off); off += A(NT);
    const int cb_d1 = 0, cb_d2 = N1, cb_d12 = N1 + N2;
    const int cb_s1 = N1 + 2 * N2, cb_s2 = N1 + 2 * N2 + N0;

    hipMemsetAsync((void*)cur, 0, (size_t)NT * sizeof(int), stream);

    // x_node -> fp16; W -> split bf16
    long n2 = (long)N0 * D / 2;
    f2h_kernel<<<(n2 + 255) / 256, 256, 0, stream>>>((const float2*)x_node,
                                                     (__half2*)xh, n2);
    wsplit_kernel<<<(3 * D * D + 255) / 256, 256, 0, stream>>>(W1, W2, W12,
                                                               Whi, Wlo);

    // XCD-partitioned ELL fills, paired jobs (3 dispatches; pairs sized so
    // combined per-XCD write windows stay ~L2-resident)
    FillJob jd1 = {ei1_dst, ei1_src, ew1, pay_d1, cb_d1, CAP1, E1, N1};
    FillJob jd2 = {ei2_dst, ei2_src, ew2, pay_d2, cb_d2, CAP1, E2, N2};
    FillJob jd12 = {ei12_dst, ei12_src, nullptr, pay_d12, cb_d12, CAP2, E12, N2};
    FillJob js1 = {ei1_src, ei1_dst, nullptr, pay_s1, cb_s1, CAP2, E1, N0};
    FillJob js2 = {ei2_src, ei2_dst, ew2, pay_s2, cb_s2, CAP2, E2, N0};
    FillJobs2 P1 = {{jd1, jd2}};
    FillJobs2 P2 = {{jd12, js1}};
    FillJobs2 P3 = {{js2, js2}};
    fill_pair_kernel<<<dim3(4096, 2), 256, 0, stream>>>(P1, cur);
    fill_pair_kernel<<<dim3(4096, 2), 256, 0, stream>>>(P2, cur);
    fill_pair_kernel<<<dim3(4096, 1), 256, 0, stream>>>(P3, cur);

    // aggregations
    auto blocks = [](int n) { return (n + 3) / 4; };
    aggh_kernel<true><<<blocks(N1), 256, 0, stream>>>(
        xh, D, cur + cb_d1, CAP1, pay_d1, x1, net1h, D, 0, N1);
    aggh_kernel<true><<<blocks(N2), 256, 0, stream>>>(
        xh, D, cur + cb_d2, CAP1, pay_d2, x2, combo, 2 * D, 0, N2);
    aggh_kernel<false><<<blocks(N2), 256, 0, stream>>>(
        net1h, D, cur + cb_d12, CAP2, pay_d12, x2, combo, 2 * D, D, N2);
    aggf_kernel<<<blocks(N0), 256, 0, stream>>>(net1h, cur + cb_s1, CAP2,
                                                pay_s1, pre1, N0);
    agg2_kernel<<<blocks(N0), 256, 0, stream>>>(combo, cur + cb_s2, CAP2,
                                                pay_s2, pre2, pre3, N0);

    // fused MFMA tail: 3x(linear+relu) + attention (pre3 aliases out)
    mfma_tail_kernel<<<(N0 + 63) / 64, 512, 0, stream>>>(
        pre1, pre2, pre3, Whi, Wlo, b1, b2, b12, att, out, N0);
}